// Round 5
// baseline (1348.458 us; speedup 1.0000x reference)
//
#include <hip/hip_runtime.h>
#include <hip/hip_bf16.h>
#include <math.h>

#define N_NODES 50000
#define N_EDGES 800000
#define NUM_GRAPHS 500
#define F_IN 128
#define HID 256
#define NCLS 10

// ---------------- GEMM: C[N,M] = A[N,K] @ B[K,M] (+ bias) ----------------
// 128x128 tile, BK=16, 256 threads, 8x8 accum, double-buffered LDS,
// one barrier per K-tile, short staging-register liveness.
#define TBM 128
#define TBN 128
#define TBK 16

__global__ __launch_bounds__(256) void gemm_bias(
    const float* __restrict__ A, const float* __restrict__ B,
    const float* __restrict__ bias, float* __restrict__ C,
    int N, int K, int M) {
  __shared__ float As[2][TBK][TBM + 4];  // transposed A tiles
  __shared__ float Bs[2][TBK][TBN];
  const int row0 = blockIdx.x * TBM;
  const int col0 = blockIdx.y * TBN;
  const int t = threadIdx.x;
  const int tx = t & 15, ty = t >> 4;
  const int rA0 = t >> 2, kA = (t & 3) * 4;   // A: row 0..63 (+64), k-vec
  const int kB0 = t >> 5, cB = (t & 31) * 4;  // B: k 0..7 (+8), col-vec
  float acc[8][8] = {};
  float4 a0, a1, b0, b1;

  auto gload = [&](int k0) {
    int gr0 = row0 + rA0, gr1 = row0 + rA0 + 64;
    a0 = (gr0 < N) ? *(const float4*)(A + (size_t)gr0 * K + k0 + kA)
                   : make_float4(0.f, 0.f, 0.f, 0.f);
    a1 = (gr1 < N) ? *(const float4*)(A + (size_t)gr1 * K + k0 + kA)
                   : make_float4(0.f, 0.f, 0.f, 0.f);
    b0 = *(const float4*)(B + (size_t)(k0 + kB0) * M + col0 + cB);
    b1 = *(const float4*)(B + (size_t)(k0 + kB0 + 8) * M + col0 + cB);
  };
  auto lstore = [&](int buf) {
    As[buf][kA + 0][rA0] = a0.x; As[buf][kA + 1][rA0] = a0.y;
    As[buf][kA + 2][rA0] = a0.z; As[buf][kA + 3][rA0] = a0.w;
    As[buf][kA + 0][rA0 + 64] = a1.x; As[buf][kA + 1][rA0 + 64] = a1.y;
    As[buf][kA + 2][rA0 + 64] = a1.z; As[buf][kA + 3][rA0 + 64] = a1.w;
    *(float4*)&Bs[buf][kB0][cB] = b0;
    *(float4*)&Bs[buf][kB0 + 8][cB] = b1;
  };
  auto fma_tile = [&](int buf) {
#pragma unroll
    for (int k = 0; k < TBK; ++k) {
      float a[8], b[8];
      *(float4*)&a[0] = *(const float4*)&As[buf][k][ty * 4];
      *(float4*)&a[4] = *(const float4*)&As[buf][k][ty * 4 + 64];
      *(float4*)&b[0] = *(const float4*)&Bs[buf][k][tx * 4];
      *(float4*)&b[4] = *(const float4*)&Bs[buf][k][tx * 4 + 64];
#pragma unroll
      for (int i = 0; i < 8; ++i)
#pragma unroll
        for (int j = 0; j < 8; ++j) acc[i][j] += a[i] * b[j];
    }
  };

  gload(0);
  lstore(0);
  __syncthreads();
  const int T = K / TBK;
  for (int tt = 1; tt < T; ++tt) {
    gload(tt * TBK);        // fetch next tile
    lstore(tt & 1);         // stage into the other buffer (regs die here)
    fma_tile((tt - 1) & 1); // compute current buffer
    __syncthreads();
  }
  fma_tile((T - 1) & 1);

#pragma unroll
  for (int ih = 0; ih < 2; ++ih) {
#pragma unroll
    for (int i = 0; i < 4; ++i) {
      int gr = row0 + ih * 64 + ty * 4 + i;
      if (gr < N) {
#pragma unroll
        for (int jh = 0; jh < 2; ++jh) {
          int gc = col0 + jh * 64 + tx * 4;
          float4 v;
          v.x = acc[ih * 4 + i][jh * 4 + 0];
          v.y = acc[ih * 4 + i][jh * 4 + 1];
          v.z = acc[ih * 4 + i][jh * 4 + 2];
          v.w = acc[ih * 4 + i][jh * 4 + 3];
          if (bias) {
            v.x += bias[gc + 0];
            v.y += bias[gc + 1];
            v.z += bias[gc + 2];
            v.w += bias[gc + 3];
          }
          *(float4*)(C + (size_t)gr * M + gc) = v;
        }
      }
    }
  }
}

// ---------------- degree accumulation ----------------
__global__ __launch_bounds__(256) void deg_accum(
    const int* __restrict__ dst, const float* __restrict__ ew,
    float* deg, int* cnt, int E) {
  int e = blockIdx.x * 256 + threadIdx.x;
  if (e < E) {
    int d = dst[e];
    atomicAdd(&deg[d], ew[e]);
    atomicAdd(&cnt[d], 1);
  }
}

// ---------------- hierarchical exclusive scan + dinv ----------------
__global__ __launch_bounds__(256) void scan_p1(const int* __restrict__ cnt,
                                               const float* __restrict__ deg,
                                               float* __restrict__ dinv,
                                               int* __restrict__ bsum, int n) {
  __shared__ int s[256];
  int i = blockIdx.x * 256 + threadIdx.x;
  s[threadIdx.x] = (i < n) ? cnt[i] : 0;
  if (i < n) dinv[i] = rsqrtf(deg[i] + 1.0f);  // + self-loop weight, always > 0
  __syncthreads();
  for (int off = 128; off > 0; off >>= 1) {
    if (threadIdx.x < off) s[threadIdx.x] += s[threadIdx.x + off];
    __syncthreads();
  }
  if (threadIdx.x == 0) bsum[blockIdx.x] = s[0];
}

__global__ __launch_bounds__(256) void scan_p2(int* __restrict__ bsum, int nb,
                                               int* __restrict__ total_out) {
  __shared__ int s[256];
  int t = threadIdx.x;
  int v = (t < nb) ? bsum[t] : 0;
  s[t] = v;
  __syncthreads();
  for (int off = 1; off < 256; off <<= 1) {
    int u = (t >= off) ? s[t - off] : 0;
    __syncthreads();
    s[t] += u;
    __syncthreads();
  }
  if (t < nb) bsum[t] = s[t] - v;  // exclusive
  if (t == 255) *total_out = s[255];
}

__global__ __launch_bounds__(256) void scan_p3(const int* __restrict__ cnt,
                                               const int* __restrict__ bsum,
                                               int* __restrict__ row_ptr, int n) {
  __shared__ int s[256];
  int i = blockIdx.x * 256 + threadIdx.x;
  int t = threadIdx.x;
  int v = (i < n) ? cnt[i] : 0;
  s[t] = v;
  __syncthreads();
  for (int off = 1; off < 256; off <<= 1) {
    int u = (t >= off) ? s[t - off] : 0;
    __syncthreads();
    s[t] += u;
    __syncthreads();
  }
  if (i < n) row_ptr[i] = bsum[blockIdx.x] + s[t] - v;
}

// ---------------- CSR fill (separate src / coef arrays) ----------------
__global__ __launch_bounds__(256) void csr_fill(
    const int* __restrict__ src, const int* __restrict__ dst,
    const float* __restrict__ ew, const float* __restrict__ dinv,
    const int* __restrict__ row_ptr, int* cursor,
    int* __restrict__ csr_src, float* __restrict__ csr_coef, int E) {
  int e = blockIdx.x * 256 + threadIdx.x;
  if (e < E) {
    int s = src[e], d = dst[e];
    int pos = atomicAdd(&cursor[d], 1);
    int idx = row_ptr[d] + pos;
    csr_src[idx] = s;
    csr_coef[idx] = dinv[s] * ew[e] * dinv[d];
  }
}

// -- aggregation + bias + ELU: one wave/node, 4 nodes/block, pipelined entries --
__global__ __launch_bounds__(256) void gather_elu(
    const float* __restrict__ hW, const float* __restrict__ dinv,
    const int* __restrict__ row_ptr, const int* __restrict__ csr_src,
    const float* __restrict__ csr_coef, const float* __restrict__ bias,
    float* __restrict__ out) {
  const int wave = threadIdx.x >> 6;
  const int lane = threadIdx.x & 63;
  const int n = blockIdx.x * 4 + wave;
  if (n >= N_NODES) return;
  const float4* hw4 = (const float4*)hW;  // 64 float4 per row
  const int start = row_ptr[n], end = row_ptr[n + 1];
  const float di = dinv[n];
  const float cself = di * di;
  float4 h = hw4[(size_t)n * 64 + lane];
  float4 acc;
  acc.x = cself * h.x; acc.y = cself * h.y;
  acc.z = cself * h.z; acc.w = cself * h.w;
  const int npairs = (end - start) >> 1;
  int e = start;
  if (npairs > 0) {
    // prime: load first pair's entries
    int s0 = csr_src[e], s1 = csr_src[e + 1];
    float w0 = csr_coef[e], w1 = csr_coef[e + 1];
    for (int p = 1; p < npairs; ++p) {
      e += 2;
      // issue row loads for current entries
      float4 v0 = hw4[(size_t)s0 * 64 + lane];
      float4 v1 = hw4[(size_t)s1 * 64 + lane];
      // load next pair's entries while rows are in flight
      int t0 = csr_src[e], t1 = csr_src[e + 1];
      float u0 = csr_coef[e], u1 = csr_coef[e + 1];
      acc.x += w0 * v0.x + w1 * v1.x;
      acc.y += w0 * v0.y + w1 * v1.y;
      acc.z += w0 * v0.z + w1 * v1.z;
      acc.w += w0 * v0.w + w1 * v1.w;
      s0 = t0; s1 = t1; w0 = u0; w1 = u1;
    }
    // drain last pair
    float4 v0 = hw4[(size_t)s0 * 64 + lane];
    float4 v1 = hw4[(size_t)s1 * 64 + lane];
    acc.x += w0 * v0.x + w1 * v1.x;
    acc.y += w0 * v0.y + w1 * v1.y;
    acc.z += w0 * v0.z + w1 * v1.z;
    acc.w += w0 * v0.w + w1 * v1.w;
    e += 2;
  }
  if (e < end) {  // odd tail
    int s0 = csr_src[e];
    float w0 = csr_coef[e];
    float4 v0 = hw4[(size_t)s0 * 64 + lane];
    acc.x += w0 * v0.x;
    acc.y += w0 * v0.y;
    acc.z += w0 * v0.z;
    acc.w += w0 * v0.w;
  }
  float4 bb = ((const float4*)bias)[lane];
  acc.x += bb.x; acc.y += bb.y; acc.z += bb.z; acc.w += bb.w;
  acc.x = (acc.x > 0.f) ? acc.x : expm1f(acc.x);
  acc.y = (acc.y > 0.f) ? acc.y : expm1f(acc.y);
  acc.z = (acc.z > 0.f) ? acc.z : expm1f(acc.z);
  acc.w = (acc.w > 0.f) ? acc.w : expm1f(acc.w);
  ((float4*)out)[(size_t)n * 64 + lane] = acc;
}

// ---------------- pooling (sorted batch -> ranges) + final linear ----------------
__global__ __launch_bounds__(256) void find_start(const int* __restrict__ batch,
                                                  int* __restrict__ gstart) {
  int g = blockIdx.x * 256 + threadIdx.x;
  if (g <= NUM_GRAPHS) {
    int lo = 0, hi = N_NODES;
    while (lo < hi) {
      int mid = (lo + hi) >> 1;
      if (batch[mid] < g) lo = mid + 1; else hi = mid;
    }
    gstart[g] = lo;
  }
}

__global__ __launch_bounds__(256) void pool_final(
    const float* __restrict__ h, const int* __restrict__ gstart,
    const float* __restrict__ W, const float* __restrict__ b,
    float* __restrict__ out) {
  int g = blockIdx.x;
  __shared__ float part[NCLS * 256];
  int f = threadIdx.x;
  int s = gstart[g], e = gstart[g + 1];
  float sum = 0.f;
  for (int n = s; n < e; ++n) sum += h[(size_t)n * HID + f];
  float v = sum / fmaxf((float)(e - s), 1.0f);
#pragma unroll
  for (int c = 0; c < NCLS; ++c) part[c * 256 + f] = v * W[f * NCLS + c];
  __syncthreads();
  for (int off = 128; off > 0; off >>= 1) {
    if (f < off) {
#pragma unroll
      for (int c = 0; c < NCLS; ++c) part[c * 256 + f] += part[c * 256 + f + off];
    }
    __syncthreads();
  }
  if (f < NCLS) out[g * NCLS + f] = part[f * 256] + b[f];
}

extern "C" void kernel_launch(void* const* d_in, const int* in_sizes, int n_in,
                              void* d_out, int out_size, void* d_ws, size_t ws_size,
                              hipStream_t stream) {
  const float* x = (const float*)d_in[0];
  const int* ei = (const int*)d_in[1];
  const int* e_src = ei;
  const int* e_dst = ei + N_EDGES;
  const float* ea = (const float*)d_in[2];
  // d_in[3] = edge_type: unused (edge_dim=1 mixing carries no per-type params)
  const int* batch = (const int*)d_in[4];
  const float* enc1_w = (const float*)d_in[5];
  const float* enc1_b = (const float*)d_in[6];
  const float* enc2_w = (const float*)d_in[7];
  const float* enc2_b = (const float*)d_in[8];
  const float* conv_ws = (const float*)d_in[9];
  const float* conv_bs = (const float*)d_in[10];
  const float* lin1_w = (const float*)d_in[11];
  const float* lin1_b = (const float*)d_in[12];
  float* out = (float*)d_out;

  char* w = (char*)d_ws;
  size_t off = 0;
  auto alloc = [&](size_t bytes) {
    size_t o = off;
    off = (off + bytes + 255) & ~(size_t)255;
    return (void*)(w + o);
  };
  float* bufA = (float*)alloc((size_t)N_NODES * HID * 4);
  float* bufB = (float*)alloc((size_t)N_NODES * HID * 4);
  float* deg = (float*)alloc((size_t)N_NODES * 4);
  float* dinv = (float*)alloc((size_t)N_NODES * 4);
  int* cnt = (int*)alloc((size_t)N_NODES * 4);
  int* row_ptr = (int*)alloc((size_t)(N_NODES + 1) * 4);
  int* cursor = (int*)alloc((size_t)N_NODES * 4);
  int* bsum = (int*)alloc((size_t)256 * 4);
  int* csr_src = (int*)alloc((size_t)N_EDGES * 4);
  float* csr_coef = (float*)alloc((size_t)N_EDGES * 4);
  int* gstart = (int*)alloc((size_t)(NUM_GRAPHS + 1) * 4);
  (void)ws_size; (void)in_sizes; (void)n_in; (void)out_size;

  hipMemsetAsync(deg, 0, (size_t)N_NODES * 4, stream);
  hipMemsetAsync(cnt, 0, (size_t)N_NODES * 4, stream);
  hipMemsetAsync(cursor, 0, (size_t)N_NODES * 4, stream);

  const int nb_nodes = (N_NODES + 255) / 256;  // 196
  const int nb_edges = (N_EDGES + 255) / 256;

  // graph normalization + CSR (independent of features; built once per call)
  deg_accum<<<nb_edges, 256, 0, stream>>>(e_dst, ea, deg, cnt, N_EDGES);
  scan_p1<<<nb_nodes, 256, 0, stream>>>(cnt, deg, dinv, bsum, N_NODES);
  scan_p2<<<1, 256, 0, stream>>>(bsum, nb_nodes, row_ptr + N_NODES);
  scan_p3<<<nb_nodes, 256, 0, stream>>>(cnt, bsum, row_ptr, N_NODES);
  csr_fill<<<nb_edges, 256, 0, stream>>>(e_src, e_dst, ea, dinv, row_ptr, cursor,
                                         csr_src, csr_coef, N_EDGES);
  find_start<<<(NUM_GRAPHS + 256) / 256, 256, 0, stream>>>(batch, gstart);

  const int gR = (N_NODES + TBM - 1) / TBM;  // 391

  // encoder: h0 = x@enc1_w + b (N,128) -> bufB ; h1 = h0@enc2_w + b (N,256) -> bufA
  {
    dim3 grid(gR, F_IN / TBN);
    gemm_bias<<<grid, 256, 0, stream>>>(x, enc1_w, enc1_b, bufB, N_NODES, F_IN, F_IN);
  }
  {
    dim3 grid(gR, HID / TBN);
    gemm_bias<<<grid, 256, 0, stream>>>(bufB, enc2_w, enc2_b, bufA, N_NODES, F_IN, HID);
  }

  // 4 GCN layers: hW = h@W (bufA->bufB); aggregate+bias+ELU (bufB->bufA)
  for (int layer = 0; layer < 4; ++layer) {
    dim3 grid(gR, HID / TBN);
    gemm_bias<<<grid, 256, 0, stream>>>(bufA, conv_ws + (size_t)layer * HID * HID,
                                        nullptr, bufB, N_NODES, HID, HID);
    gather_elu<<<(N_NODES + 3) / 4, 256, 0, stream>>>(
        bufB, dinv, row_ptr, csr_src, csr_coef,
        conv_bs + (size_t)layer * HID, bufA);
  }

  // deterministic mean-pool per graph + final linear (fused)
  pool_final<<<NUM_GRAPHS, 256, 0, stream>>>(bufA, gstart, lin1_w, lin1_b, out);
}

// Round 6
// 1152.128 us; speedup vs baseline: 1.1704x; 1.1704x over previous
//
#include <hip/hip_runtime.h>
#include <hip/hip_bf16.h>
#include <math.h>

#define N_NODES 50000
#define N_EDGES 800000
#define NUM_GRAPHS 500
#define F_IN 128
#define HID 256
#define NCLS 10

// ---------------- GEMM: C[N,M] = A[N,K] @ B[K,M] (+ bias) ----------------
// 128x128 tile, BK=16, 256 threads, 8x8 accum per thread, float4 LDS traffic.
// (round-2/3 version: best measured; register-prefetch/dbuf variants blew VGPR)
#define TBM 128
#define TBN 128
#define TBK 16

__global__ __launch_bounds__(256) void gemm_bias(
    const float* __restrict__ A, const float* __restrict__ B,
    const float* __restrict__ bias, float* __restrict__ C,
    int N, int K, int M) {
  __shared__ float As[TBK][TBM + 4];  // transposed A tile; +4 keeps 16B align
  __shared__ float Bs[TBK][TBN];
  const int row0 = blockIdx.x * TBM;
  const int col0 = blockIdx.y * TBN;
  const int t = threadIdx.x;
  const int tx = t & 15, ty = t >> 4;
  float acc[8][8] = {};
  for (int k0 = 0; k0 < K; k0 += TBK) {
#pragma unroll
    for (int i = 0; i < 2; ++i) {
      int idx = t + i * 256;
      int row = idx >> 2;
      int kv = (idx & 3) * 4;
      int gr = row0 + row;
      float4 v = make_float4(0.f, 0.f, 0.f, 0.f);
      if (gr < N) v = *(const float4*)(A + (size_t)gr * K + k0 + kv);
      As[kv + 0][row] = v.x;
      As[kv + 1][row] = v.y;
      As[kv + 2][row] = v.z;
      As[kv + 3][row] = v.w;
    }
#pragma unroll
    for (int i = 0; i < 2; ++i) {
      int idx = t + i * 256;
      int k = idx >> 5;
      int c = (idx & 31) * 4;
      *(float4*)&Bs[k][c] = *(const float4*)(B + (size_t)(k0 + k) * M + col0 + c);
    }
    __syncthreads();
#pragma unroll
    for (int k = 0; k < TBK; ++k) {
      float a[8], b[8];
      *(float4*)&a[0] = *(const float4*)&As[k][ty * 4];
      *(float4*)&a[4] = *(const float4*)&As[k][ty * 4 + 64];
      *(float4*)&b[0] = *(const float4*)&Bs[k][tx * 4];
      *(float4*)&b[4] = *(const float4*)&Bs[k][tx * 4 + 64];
#pragma unroll
      for (int i = 0; i < 8; ++i)
#pragma unroll
        for (int j = 0; j < 8; ++j) acc[i][j] += a[i] * b[j];
    }
    __syncthreads();
  }
#pragma unroll
  for (int ih = 0; ih < 2; ++ih) {
#pragma unroll
    for (int i = 0; i < 4; ++i) {
      int gr = row0 + ih * 64 + ty * 4 + i;
      if (gr < N) {
#pragma unroll
        for (int jh = 0; jh < 2; ++jh) {
          int gc = col0 + jh * 64 + tx * 4;
          float4 v;
          v.x = acc[ih * 4 + i][jh * 4 + 0];
          v.y = acc[ih * 4 + i][jh * 4 + 1];
          v.z = acc[ih * 4 + i][jh * 4 + 2];
          v.w = acc[ih * 4 + i][jh * 4 + 3];
          if (bias) {
            v.x += bias[gc + 0];
            v.y += bias[gc + 1];
            v.z += bias[gc + 2];
            v.w += bias[gc + 3];
          }
          *(float4*)(C + (size_t)gr * M + gc) = v;
        }
      }
    }
  }
}

// ---------------- degree accumulation ----------------
__global__ __launch_bounds__(256) void deg_accum(
    const int* __restrict__ dst, const float* __restrict__ ew,
    float* deg, int* cnt, int E) {
  int e = blockIdx.x * 256 + threadIdx.x;
  if (e < E) {
    int d = dst[e];
    atomicAdd(&deg[d], ew[e]);
    atomicAdd(&cnt[d], 1);
  }
}

// ---------------- hierarchical exclusive scan + dinv ----------------
__global__ __launch_bounds__(256) void scan_p1(const int* __restrict__ cnt,
                                               const float* __restrict__ deg,
                                               float* __restrict__ dinv,
                                               int* __restrict__ bsum, int n) {
  __shared__ int s[256];
  int i = blockIdx.x * 256 + threadIdx.x;
  s[threadIdx.x] = (i < n) ? cnt[i] : 0;
  if (i < n) dinv[i] = rsqrtf(deg[i] + 1.0f);  // + self-loop weight, always > 0
  __syncthreads();
  for (int off = 128; off > 0; off >>= 1) {
    if (threadIdx.x < off) s[threadIdx.x] += s[threadIdx.x + off];
    __syncthreads();
  }
  if (threadIdx.x == 0) bsum[blockIdx.x] = s[0];
}

__global__ __launch_bounds__(256) void scan_p2(int* __restrict__ bsum, int nb,
                                               int* __restrict__ total_out) {
  __shared__ int s[256];
  int t = threadIdx.x;
  int v = (t < nb) ? bsum[t] : 0;
  s[t] = v;
  __syncthreads();
  for (int off = 1; off < 256; off <<= 1) {
    int u = (t >= off) ? s[t - off] : 0;
    __syncthreads();
    s[t] += u;
    __syncthreads();
  }
  if (t < nb) bsum[t] = s[t] - v;  // exclusive
  if (t == 255) *total_out = s[255];
}

__global__ __launch_bounds__(256) void scan_p3(const int* __restrict__ cnt,
                                               const int* __restrict__ bsum,
                                               int* __restrict__ row_ptr, int n) {
  __shared__ int s[256];
  int i = blockIdx.x * 256 + threadIdx.x;
  int t = threadIdx.x;
  int v = (i < n) ? cnt[i] : 0;
  s[t] = v;
  __syncthreads();
  for (int off = 1; off < 256; off <<= 1) {
    int u = (t >= off) ? s[t - off] : 0;
    __syncthreads();
    s[t] += u;
    __syncthreads();
  }
  if (i < n) row_ptr[i] = bsum[blockIdx.x] + s[t] - v;
}

// ---------------- CSR fill (separate src / coef arrays) ----------------
__global__ __launch_bounds__(256) void csr_fill(
    const int* __restrict__ src, const int* __restrict__ dst,
    const float* __restrict__ ew, const float* __restrict__ dinv,
    const int* __restrict__ row_ptr, int* cursor,
    int* __restrict__ csr_src, float* __restrict__ csr_coef, int E) {
  int e = blockIdx.x * 256 + threadIdx.x;
  if (e < E) {
    int s = src[e], d = dst[e];
    int pos = atomicAdd(&cursor[d], 1);
    int idx = row_ptr[d] + pos;
    csr_src[idx] = s;
    csr_coef[idx] = dinv[s] * ew[e] * dinv[d];
  }
}

// -- aggregation + bias + ELU: one wave/node, 4 nodes/block, pipelined entries --
__global__ __launch_bounds__(256) void gather_elu(
    const float* __restrict__ hW, const float* __restrict__ dinv,
    const int* __restrict__ row_ptr, const int* __restrict__ csr_src,
    const float* __restrict__ csr_coef, const float* __restrict__ bias,
    float* __restrict__ out) {
  const int wave = threadIdx.x >> 6;
  const int lane = threadIdx.x & 63;
  const int n = blockIdx.x * 4 + wave;
  if (n >= N_NODES) return;
  const float4* hw4 = (const float4*)hW;  // 64 float4 per row
  const int start = row_ptr[n], end = row_ptr[n + 1];
  const float di = dinv[n];
  const float cself = di * di;
  float4 h = hw4[(size_t)n * 64 + lane];
  float4 acc;
  acc.x = cself * h.x; acc.y = cself * h.y;
  acc.z = cself * h.z; acc.w = cself * h.w;
  const int npairs = (end - start) >> 1;
  int e = start;
  if (npairs > 0) {
    // prime: load first pair's entries
    int s0 = csr_src[e], s1 = csr_src[e + 1];
    float w0 = csr_coef[e], w1 = csr_coef[e + 1];
    for (int p = 1; p < npairs; ++p) {
      e += 2;
      // issue row loads for current entries
      float4 v0 = hw4[(size_t)s0 * 64 + lane];
      float4 v1 = hw4[(size_t)s1 * 64 + lane];
      // load next pair's entries while rows are in flight
      int t0 = csr_src[e], t1 = csr_src[e + 1];
      float u0 = csr_coef[e], u1 = csr_coef[e + 1];
      acc.x += w0 * v0.x + w1 * v1.x;
      acc.y += w0 * v0.y + w1 * v1.y;
      acc.z += w0 * v0.z + w1 * v1.z;
      acc.w += w0 * v0.w + w1 * v1.w;
      s0 = t0; s1 = t1; w0 = u0; w1 = u1;
    }
    // drain last pair
    float4 v0 = hw4[(size_t)s0 * 64 + lane];
    float4 v1 = hw4[(size_t)s1 * 64 + lane];
    acc.x += w0 * v0.x + w1 * v1.x;
    acc.y += w0 * v0.y + w1 * v1.y;
    acc.z += w0 * v0.z + w1 * v1.z;
    acc.w += w0 * v0.w + w1 * v1.w;
    e += 2;
  }
  if (e < end) {  // odd tail
    int s0 = csr_src[e];
    float w0 = csr_coef[e];
    float4 v0 = hw4[(size_t)s0 * 64 + lane];
    acc.x += w0 * v0.x;
    acc.y += w0 * v0.y;
    acc.z += w0 * v0.z;
    acc.w += w0 * v0.w;
  }
  float4 bb = ((const float4*)bias)[lane];
  acc.x += bb.x; acc.y += bb.y; acc.z += bb.z; acc.w += bb.w;
  acc.x = (acc.x > 0.f) ? acc.x : expm1f(acc.x);
  acc.y = (acc.y > 0.f) ? acc.y : expm1f(acc.y);
  acc.z = (acc.z > 0.f) ? acc.z : expm1f(acc.z);
  acc.w = (acc.w > 0.f) ? acc.w : expm1f(acc.w);
  ((float4*)out)[(size_t)n * 64 + lane] = acc;
}

// ---------------- pooling (sorted batch -> ranges) + final linear ----------------
__global__ __launch_bounds__(256) void find_start(const int* __restrict__ batch,
                                                  int* __restrict__ gstart) {
  int g = blockIdx.x * 256 + threadIdx.x;
  if (g <= NUM_GRAPHS) {
    int lo = 0, hi = N_NODES;
    while (lo < hi) {
      int mid = (lo + hi) >> 1;
      if (batch[mid] < g) lo = mid + 1; else hi = mid;
    }
    gstart[g] = lo;
  }
}

__global__ __launch_bounds__(256) void pool_final(
    const float* __restrict__ h, const int* __restrict__ gstart,
    const float* __restrict__ W, const float* __restrict__ b,
    float* __restrict__ out) {
  int g = blockIdx.x;
  __shared__ float part[NCLS * 256];
  int f = threadIdx.x;
  int s = gstart[g], e = gstart[g + 1];
  float sum = 0.f;
  for (int n = s; n < e; ++n) sum += h[(size_t)n * HID + f];
  float v = sum / fmaxf((float)(e - s), 1.0f);
#pragma unroll
  for (int c = 0; c < NCLS; ++c) part[c * 256 + f] = v * W[f * NCLS + c];
  __syncthreads();
  for (int off = 128; off > 0; off >>= 1) {
    if (f < off) {
#pragma unroll
      for (int c = 0; c < NCLS; ++c) part[c * 256 + f] += part[c * 256 + f + off];
    }
    __syncthreads();
  }
  if (f < NCLS) out[g * NCLS + f] = part[f * 256] + b[f];
}

extern "C" void kernel_launch(void* const* d_in, const int* in_sizes, int n_in,
                              void* d_out, int out_size, void* d_ws, size_t ws_size,
                              hipStream_t stream) {
  const float* x = (const float*)d_in[0];
  const int* ei = (const int*)d_in[1];
  const int* e_src = ei;
  const int* e_dst = ei + N_EDGES;
  const float* ea = (const float*)d_in[2];
  // d_in[3] = edge_type: unused (edge_dim=1 mixing carries no per-type params)
  const int* batch = (const int*)d_in[4];
  const float* enc1_w = (const float*)d_in[5];
  const float* enc1_b = (const float*)d_in[6];
  const float* enc2_w = (const float*)d_in[7];
  const float* enc2_b = (const float*)d_in[8];
  const float* conv_ws = (const float*)d_in[9];
  const float* conv_bs = (const float*)d_in[10];
  const float* lin1_w = (const float*)d_in[11];
  const float* lin1_b = (const float*)d_in[12];
  float* out = (float*)d_out;

  char* w = (char*)d_ws;
  size_t off = 0;
  auto alloc = [&](size_t bytes) {
    size_t o = off;
    off = (off + bytes + 255) & ~(size_t)255;
    return (void*)(w + o);
  };
  float* bufA = (float*)alloc((size_t)N_NODES * HID * 4);
  float* bufB = (float*)alloc((size_t)N_NODES * HID * 4);
  float* deg = (float*)alloc((size_t)N_NODES * 4);
  float* dinv = (float*)alloc((size_t)N_NODES * 4);
  int* cnt = (int*)alloc((size_t)N_NODES * 4);
  int* row_ptr = (int*)alloc((size_t)(N_NODES + 1) * 4);
  int* cursor = (int*)alloc((size_t)N_NODES * 4);
  int* bsum = (int*)alloc((size_t)256 * 4);
  int* csr_src = (int*)alloc((size_t)N_EDGES * 4);
  float* csr_coef = (float*)alloc((size_t)N_EDGES * 4);
  int* gstart = (int*)alloc((size_t)(NUM_GRAPHS + 1) * 4);
  (void)ws_size; (void)in_sizes; (void)n_in; (void)out_size;

  hipMemsetAsync(deg, 0, (size_t)N_NODES * 4, stream);
  hipMemsetAsync(cnt, 0, (size_t)N_NODES * 4, stream);
  hipMemsetAsync(cursor, 0, (size_t)N_NODES * 4, stream);

  const int nb_nodes = (N_NODES + 255) / 256;  // 196
  const int nb_edges = (N_EDGES + 255) / 256;

  // graph normalization + CSR (independent of features; built once per call)
  deg_accum<<<nb_edges, 256, 0, stream>>>(e_dst, ea, deg, cnt, N_EDGES);
  scan_p1<<<nb_nodes, 256, 0, stream>>>(cnt, deg, dinv, bsum, N_NODES);
  scan_p2<<<1, 256, 0, stream>>>(bsum, nb_nodes, row_ptr + N_NODES);
  scan_p3<<<nb_nodes, 256, 0, stream>>>(cnt, bsum, row_ptr, N_NODES);
  csr_fill<<<nb_edges, 256, 0, stream>>>(e_src, e_dst, ea, dinv, row_ptr, cursor,
                                         csr_src, csr_coef, N_EDGES);
  find_start<<<(NUM_GRAPHS + 256) / 256, 256, 0, stream>>>(batch, gstart);

  const int gR = (N_NODES + TBM - 1) / TBM;  // 391

  // encoder: h0 = x@enc1_w + b (N,128) -> bufB ; h1 = h0@enc2_w + b (N,256) -> bufA
  {
    dim3 grid(gR, F_IN / TBN);
    gemm_bias<<<grid, 256, 0, stream>>>(x, enc1_w, enc1_b, bufB, N_NODES, F_IN, F_IN);
  }
  {
    dim3 grid(gR, HID / TBN);
    gemm_bias<<<grid, 256, 0, stream>>>(bufB, enc2_w, enc2_b, bufA, N_NODES, F_IN, HID);
  }

  // 4 GCN layers: hW = h@W (bufA->bufB); aggregate+bias+ELU (bufB->bufA)
  for (int layer = 0; layer < 4; ++layer) {
    dim3 grid(gR, HID / TBN);
    gemm_bias<<<grid, 256, 0, stream>>>(bufA, conv_ws + (size_t)layer * HID * HID,
                                        nullptr, bufB, N_NODES, HID, HID);
    gather_elu<<<(N_NODES + 3) / 4, 256, 0, stream>>>(
        bufB, dinv, row_ptr, csr_src, csr_coef,
        conv_bs + (size_t)layer * HID, bufA);
  }

  // deterministic mean-pool per graph + final linear (fused)
  pool_final<<<NUM_GRAPHS, 256, 0, stream>>>(bufA, gstart, lin1_w, lin1_b, out);
}

// Round 7
// 1148.484 us; speedup vs baseline: 1.1741x; 1.0032x over previous
//
#include <hip/hip_runtime.h>
#include <hip/hip_bf16.h>
#include <math.h>

#define N_NODES 50000
#define N_EDGES 800000
#define NUM_GRAPHS 500
#define F_IN 128
#define HID 256
#define NCLS 10

// ---------------- GEMM: C[N,M] = A[N,K] @ B[K,M] (+ bias) ----------------
// 128x128 tile, BK=32 (16 barriers for K=256), 256 threads, 8x8 accum,
// float4 LDS traffic. Simple 2-barrier-per-tile loop (R2 structure; the
// register-prefetch and LDS-dbuf variants both blew VGPR to ~200 -> 8% occ).
#define TBM 128
#define TBN 128
#define TBK 32

__global__ __launch_bounds__(256) void gemm_bias(
    const float* __restrict__ A, const float* __restrict__ B,
    const float* __restrict__ bias, float* __restrict__ C,
    int N, int K, int M) {
  __shared__ float As[TBK][TBM + 4];  // transposed A tile; +4 keeps 16B align
  __shared__ float Bs[TBK][TBN + 4];
  const int row0 = blockIdx.x * TBM;
  const int col0 = blockIdx.y * TBN;
  const int t = threadIdx.x;
  const int tx = t & 15, ty = t >> 4;
  float acc[8][8] = {};
  for (int k0 = 0; k0 < K; k0 += TBK) {
    // A tile: 128 rows x 32 k = 1024 float4; 4 per thread; store transposed
#pragma unroll
    for (int i = 0; i < 4; ++i) {
      int idx = t + i * 256;
      int row = idx >> 3;
      int kv = (idx & 7) * 4;
      int gr = row0 + row;
      float4 v = make_float4(0.f, 0.f, 0.f, 0.f);
      if (gr < N) v = *(const float4*)(A + (size_t)gr * K + k0 + kv);
      As[kv + 0][row] = v.x;
      As[kv + 1][row] = v.y;
      As[kv + 2][row] = v.z;
      As[kv + 3][row] = v.w;
    }
    // B tile: 32 k x 128 cols = 1024 float4; 4 per thread
#pragma unroll
    for (int i = 0; i < 4; ++i) {
      int idx = t + i * 256;
      int k = idx >> 5;
      int c = (idx & 31) * 4;
      *(float4*)&Bs[k][c] = *(const float4*)(B + (size_t)(k0 + k) * M + col0 + c);
    }
    __syncthreads();
#pragma unroll
    for (int k = 0; k < TBK; ++k) {
      float a[8], b[8];
      *(float4*)&a[0] = *(const float4*)&As[k][ty * 4];
      *(float4*)&a[4] = *(const float4*)&As[k][ty * 4 + 64];
      *(float4*)&b[0] = *(const float4*)&Bs[k][tx * 4];
      *(float4*)&b[4] = *(const float4*)&Bs[k][tx * 4 + 64];
#pragma unroll
      for (int i = 0; i < 8; ++i)
#pragma unroll
        for (int j = 0; j < 8; ++j) acc[i][j] += a[i] * b[j];
    }
    __syncthreads();
  }
#pragma unroll
  for (int ih = 0; ih < 2; ++ih) {
#pragma unroll
    for (int i = 0; i < 4; ++i) {
      int gr = row0 + ih * 64 + ty * 4 + i;
      if (gr < N) {
#pragma unroll
        for (int jh = 0; jh < 2; ++jh) {
          int gc = col0 + jh * 64 + tx * 4;
          float4 v;
          v.x = acc[ih * 4 + i][jh * 4 + 0];
          v.y = acc[ih * 4 + i][jh * 4 + 1];
          v.z = acc[ih * 4 + i][jh * 4 + 2];
          v.w = acc[ih * 4 + i][jh * 4 + 3];
          if (bias) {
            v.x += bias[gc + 0];
            v.y += bias[gc + 1];
            v.z += bias[gc + 2];
            v.w += bias[gc + 3];
          }
          *(float4*)(C + (size_t)gr * M + gc) = v;
        }
      }
    }
  }
}

// ---------------- degree accumulation ----------------
__global__ __launch_bounds__(256) void deg_accum(
    const int* __restrict__ dst, const float* __restrict__ ew,
    float* deg, int* cnt, int E) {
  int e = blockIdx.x * 256 + threadIdx.x;
  if (e < E) {
    int d = dst[e];
    atomicAdd(&deg[d], ew[e]);
    atomicAdd(&cnt[d], 1);
  }
}

// ---------------- hierarchical exclusive scan + dinv ----------------
__global__ __launch_bounds__(256) void scan_p1(const int* __restrict__ cnt,
                                               const float* __restrict__ deg,
                                               float* __restrict__ dinv,
                                               int* __restrict__ bsum, int n) {
  __shared__ int s[256];
  int i = blockIdx.x * 256 + threadIdx.x;
  s[threadIdx.x] = (i < n) ? cnt[i] : 0;
  if (i < n) dinv[i] = rsqrtf(deg[i] + 1.0f);  // + self-loop weight, always > 0
  __syncthreads();
  for (int off = 128; off > 0; off >>= 1) {
    if (threadIdx.x < off) s[threadIdx.x] += s[threadIdx.x + off];
    __syncthreads();
  }
  if (threadIdx.x == 0) bsum[blockIdx.x] = s[0];
}

__global__ __launch_bounds__(256) void scan_p2(int* __restrict__ bsum, int nb,
                                               int* __restrict__ total_out) {
  __shared__ int s[256];
  int t = threadIdx.x;
  int v = (t < nb) ? bsum[t] : 0;
  s[t] = v;
  __syncthreads();
  for (int off = 1; off < 256; off <<= 1) {
    int u = (t >= off) ? s[t - off] : 0;
    __syncthreads();
    s[t] += u;
    __syncthreads();
  }
  if (t < nb) bsum[t] = s[t] - v;  // exclusive
  if (t == 255) *total_out = s[255];
}

__global__ __launch_bounds__(256) void scan_p3(const int* __restrict__ cnt,
                                               const int* __restrict__ bsum,
                                               int* __restrict__ row_ptr, int n) {
  __shared__ int s[256];
  int i = blockIdx.x * 256 + threadIdx.x;
  int t = threadIdx.x;
  int v = (i < n) ? cnt[i] : 0;
  s[t] = v;
  __syncthreads();
  for (int off = 1; off < 256; off <<= 1) {
    int u = (t >= off) ? s[t - off] : 0;
    __syncthreads();
    s[t] += u;
    __syncthreads();
  }
  if (i < n) row_ptr[i] = bsum[blockIdx.x] + s[t] - v;
}

// ---------------- CSR fill (separate src / coef arrays) ----------------
__global__ __launch_bounds__(256) void csr_fill(
    const int* __restrict__ src, const int* __restrict__ dst,
    const float* __restrict__ ew, const float* __restrict__ dinv,
    const int* __restrict__ row_ptr, int* cursor,
    int* __restrict__ csr_src, float* __restrict__ csr_coef, int E) {
  int e = blockIdx.x * 256 + threadIdx.x;
  if (e < E) {
    int s = src[e], d = dst[e];
    int pos = atomicAdd(&cursor[d], 1);
    int idx = row_ptr[d] + pos;
    csr_src[idx] = s;
    csr_coef[idx] = dinv[s] * ew[e] * dinv[d];
  }
}

// -- aggregation + bias + ELU: one wave/node, 4 nodes/block, pipelined entries --
__global__ __launch_bounds__(256) void gather_elu(
    const float* __restrict__ hW, const float* __restrict__ dinv,
    const int* __restrict__ row_ptr, const int* __restrict__ csr_src,
    const float* __restrict__ csr_coef, const float* __restrict__ bias,
    float* __restrict__ out) {
  const int wave = threadIdx.x >> 6;
  const int lane = threadIdx.x & 63;
  const int n = blockIdx.x * 4 + wave;
  if (n >= N_NODES) return;
  const float4* hw4 = (const float4*)hW;  // 64 float4 per row
  const int start = row_ptr[n], end = row_ptr[n + 1];
  const float di = dinv[n];
  const float cself = di * di;
  float4 h = hw4[(size_t)n * 64 + lane];
  float4 acc;
  acc.x = cself * h.x; acc.y = cself * h.y;
  acc.z = cself * h.z; acc.w = cself * h.w;
  const int npairs = (end - start) >> 1;
  int e = start;
  if (npairs > 0) {
    int s0 = csr_src[e], s1 = csr_src[e + 1];
    float w0 = csr_coef[e], w1 = csr_coef[e + 1];
    for (int p = 1; p < npairs; ++p) {
      e += 2;
      float4 v0 = hw4[(size_t)s0 * 64 + lane];
      float4 v1 = hw4[(size_t)s1 * 64 + lane];
      int t0 = csr_src[e], t1 = csr_src[e + 1];
      float u0 = csr_coef[e], u1 = csr_coef[e + 1];
      acc.x += w0 * v0.x + w1 * v1.x;
      acc.y += w0 * v0.y + w1 * v1.y;
      acc.z += w0 * v0.z + w1 * v1.z;
      acc.w += w0 * v0.w + w1 * v1.w;
      s0 = t0; s1 = t1; w0 = u0; w1 = u1;
    }
    float4 v0 = hw4[(size_t)s0 * 64 + lane];
    float4 v1 = hw4[(size_t)s1 * 64 + lane];
    acc.x += w0 * v0.x + w1 * v1.x;
    acc.y += w0 * v0.y + w1 * v1.y;
    acc.z += w0 * v0.z + w1 * v1.z;
    acc.w += w0 * v0.w + w1 * v1.w;
    e += 2;
  }
  if (e < end) {  // odd tail
    int s0 = csr_src[e];
    float w0 = csr_coef[e];
    float4 v0 = hw4[(size_t)s0 * 64 + lane];
    acc.x += w0 * v0.x;
    acc.y += w0 * v0.y;
    acc.z += w0 * v0.z;
    acc.w += w0 * v0.w;
  }
  float4 bb = ((const float4*)bias)[lane];
  acc.x += bb.x; acc.y += bb.y; acc.z += bb.z; acc.w += bb.w;
  acc.x = (acc.x > 0.f) ? acc.x : expm1f(acc.x);
  acc.y = (acc.y > 0.f) ? acc.y : expm1f(acc.y);
  acc.z = (acc.z > 0.f) ? acc.z : expm1f(acc.z);
  acc.w = (acc.w > 0.f) ? acc.w : expm1f(acc.w);
  ((float4*)out)[(size_t)n * 64 + lane] = acc;
}

// ---------------- pooling (sorted batch -> ranges) + final linear ----------------
__global__ __launch_bounds__(256) void find_start(const int* __restrict__ batch,
                                                  int* __restrict__ gstart) {
  int g = blockIdx.x * 256 + threadIdx.x;
  if (g <= NUM_GRAPHS) {
    int lo = 0, hi = N_NODES;
    while (lo < hi) {
      int mid = (lo + hi) >> 1;
      if (batch[mid] < g) lo = mid + 1; else hi = mid;
    }
    gstart[g] = lo;
  }
}

__global__ __launch_bounds__(256) void pool_final(
    const float* __restrict__ h, const int* __restrict__ gstart,
    const float* __restrict__ W, const float* __restrict__ b,
    float* __restrict__ out) {
  int g = blockIdx.x;
  __shared__ float part[NCLS * 256];
  int f = threadIdx.x;
  int s = gstart[g], e = gstart[g + 1];
  float sum = 0.f;
  for (int n = s; n < e; ++n) sum += h[(size_t)n * HID + f];
  float v = sum / fmaxf((float)(e - s), 1.0f);
#pragma unroll
  for (int c = 0; c < NCLS; ++c) part[c * 256 + f] = v * W[f * NCLS + c];
  __syncthreads();
  for (int off = 128; off > 0; off >>= 1) {
    if (f < off) {
#pragma unroll
      for (int c = 0; c < NCLS; ++c) part[c * 256 + f] += part[c * 256 + f + off];
    }
    __syncthreads();
  }
  if (f < NCLS) out[g * NCLS + f] = part[f * 256] + b[f];
}

extern "C" void kernel_launch(void* const* d_in, const int* in_sizes, int n_in,
                              void* d_out, int out_size, void* d_ws, size_t ws_size,
                              hipStream_t stream) {
  const float* x = (const float*)d_in[0];
  const int* ei = (const int*)d_in[1];
  const int* e_src = ei;
  const int* e_dst = ei + N_EDGES;
  const float* ea = (const float*)d_in[2];
  // d_in[3] = edge_type: unused (edge_dim=1 mixing carries no per-type params)
  const int* batch = (const int*)d_in[4];
  const float* enc1_w = (const float*)d_in[5];
  const float* enc1_b = (const float*)d_in[6];
  const float* enc2_w = (const float*)d_in[7];
  const float* enc2_b = (const float*)d_in[8];
  const float* conv_ws = (const float*)d_in[9];
  const float* conv_bs = (const float*)d_in[10];
  const float* lin1_w = (const float*)d_in[11];
  const float* lin1_b = (const float*)d_in[12];
  float* out = (float*)d_out;

  char* w = (char*)d_ws;
  size_t off = 0;
  auto alloc = [&](size_t bytes) {
    size_t o = off;
    off = (off + bytes + 255) & ~(size_t)255;
    return (void*)(w + o);
  };
  float* bufA = (float*)alloc((size_t)N_NODES * HID * 4);
  float* bufB = (float*)alloc((size_t)N_NODES * HID * 4);
  float* deg = (float*)alloc((size_t)N_NODES * 4);
  float* dinv = (float*)alloc((size_t)N_NODES * 4);
  int* cnt = (int*)alloc((size_t)N_NODES * 4);
  int* row_ptr = (int*)alloc((size_t)(N_NODES + 1) * 4);
  int* cursor = (int*)alloc((size_t)N_NODES * 4);
  int* bsum = (int*)alloc((size_t)256 * 4);
  int* csr_src = (int*)alloc((size_t)N_EDGES * 4);
  float* csr_coef = (float*)alloc((size_t)N_EDGES * 4);
  int* gstart = (int*)alloc((size_t)(NUM_GRAPHS + 1) * 4);
  (void)ws_size; (void)in_sizes; (void)n_in; (void)out_size;

  hipMemsetAsync(deg, 0, (size_t)N_NODES * 4, stream);
  hipMemsetAsync(cnt, 0, (size_t)N_NODES * 4, stream);
  hipMemsetAsync(cursor, 0, (size_t)N_NODES * 4, stream);

  const int nb_nodes = (N_NODES + 255) / 256;  // 196
  const int nb_edges = (N_EDGES + 255) / 256;

  // graph normalization + CSR (independent of features; built once per call)
  deg_accum<<<nb_edges, 256, 0, stream>>>(e_dst, ea, deg, cnt, N_EDGES);
  scan_p1<<<nb_nodes, 256, 0, stream>>>(cnt, deg, dinv, bsum, N_NODES);
  scan_p2<<<1, 256, 0, stream>>>(bsum, nb_nodes, row_ptr + N_NODES);
  scan_p3<<<nb_nodes, 256, 0, stream>>>(cnt, bsum, row_ptr, N_NODES);
  csr_fill<<<nb_edges, 256, 0, stream>>>(e_src, e_dst, ea, dinv, row_ptr, cursor,
                                         csr_src, csr_coef, N_EDGES);
  find_start<<<(NUM_GRAPHS + 256) / 256, 256, 0, stream>>>(batch, gstart);

  const int gR = (N_NODES + TBM - 1) / TBM;  // 391

  // encoder: h0 = x@enc1_w + b (N,128) -> bufB ; h1 = h0@enc2_w + b (N,256) -> bufA
  {
    dim3 grid(gR, F_IN / TBN);
    gemm_bias<<<grid, 256, 0, stream>>>(x, enc1_w, enc1_b, bufB, N_NODES, F_IN, F_IN);
  }
  {
    dim3 grid(gR, HID / TBN);
    gemm_bias<<<grid, 256, 0, stream>>>(bufB, enc2_w, enc2_b, bufA, N_NODES, F_IN, HID);
  }

  // 4 GCN layers: hW = h@W (bufA->bufB); aggregate+bias+ELU (bufB->bufA)
  for (int layer = 0; layer < 4; ++layer) {
    dim3 grid(gR, HID / TBN);
    gemm_bias<<<grid, 256, 0, stream>>>(bufA, conv_ws + (size_t)layer * HID * HID,
                                        nullptr, bufB, N_NODES, HID, HID);
    gather_elu<<<(N_NODES + 3) / 4, 256, 0, stream>>>(
        bufB, dinv, row_ptr, csr_src, csr_coef,
        conv_bs + (size_t)layer * HID, bufA);
  }

  // deterministic mean-pool per graph + final linear (fused)
  pool_final<<<NUM_GRAPHS, 256, 0, stream>>>(bufA, gstart, lin1_w, lin1_b, out);
}

// Round 8
// 1034.243 us; speedup vs baseline: 1.3038x; 1.1105x over previous
//
#include <hip/hip_runtime.h>
#include <hip/hip_bf16.h>
#include <math.h>

#define N_NODES 50000
#define N_EDGES 800000
#define NUM_GRAPHS 500
#define F_IN 128
#define HID 256
#define NCLS 10

typedef _Float16 f16;
typedef _Float16 f16x8 __attribute__((ext_vector_type(8)));
typedef _Float16 f16x4 __attribute__((ext_vector_type(4)));
typedef float f32x4 __attribute__((ext_vector_type(4)));

// ---------------- fp32 -> (hi,lo) f16 split, elementwise (float4/thread) ------
__global__ __launch_bounds__(256) void split_f32(const float* __restrict__ in,
                                                 f16* __restrict__ hi,
                                                 f16* __restrict__ lo, int n4) {
  int i = blockIdx.x * 256 + threadIdx.x;
  if (i < n4) {
    float4 v = ((const float4*)in)[i];
    float c0 = v.x, c1 = v.y, c2 = v.z, c3 = v.w;
    f16x4 h, l;
    f16 h0 = (f16)c0; h[0] = h0; l[0] = (f16)(c0 - (float)h0);
    f16 h1 = (f16)c1; h[1] = h1; l[1] = (f16)(c1 - (float)h1);
    f16 h2 = (f16)c2; h[2] = h2; l[2] = (f16)(c2 - (float)h2);
    f16 h3 = (f16)c3; h[3] = h3; l[3] = (f16)(c3 - (float)h3);
    ((f16x4*)hi)[i] = h;
    ((f16x4*)lo)[i] = l;
  }
}

// -------- weight transpose + split: W[b][K][M] -> T[b][M][K] (hi,lo f16) ------
__global__ __launch_bounds__(256) void tsplit(const float* __restrict__ W,
                                              f16* __restrict__ Th,
                                              f16* __restrict__ Tl,
                                              int K, int Mc, int total) {
  int tid = blockIdx.x * 256 + threadIdx.x;
  if (tid < total) {
    int km = K * Mc;
    int b = tid / km;
    int rem = tid - b * km;
    int m = rem / K;
    int k = rem - m * K;
    float v = W[(size_t)b * km + (size_t)k * Mc + m];
    f16 h = (f16)v;
    Th[tid] = h;
    Tl[tid] = (f16)(v - (float)h);
  }
}

// ---------------- MFMA GEMM (f16x2 emulation), no LDS, no barriers ------------
// C[M,Nc] = (Ah+Al)[M,K] @ B[K,Nc] where B is given transposed as Bt[Nc][K].
// Block 256 thr = 4 waves (2x2), wave tile 64x64, 4x4 frags of 16x16x32 MFMA.
// A frag: lane holds A[row0+ (l&15)][k0 + (l>>4)*8 + j]; B frag symmetric on Bt.
// C/D: col = l&15, row = (l>>4)*4 + r   [verified layout, guide §3]
__global__ __launch_bounds__(256) void gemm_mfma(
    const f16* __restrict__ Ah, const f16* __restrict__ Al,
    const f16* __restrict__ Bth, const f16* __restrict__ Btl,
    const float* __restrict__ bias,
    f16* __restrict__ Ch, f16* __restrict__ Cl,
    int M, int K, int Nc) {
  const int lane = threadIdx.x & 63;
  const int wave = threadIdx.x >> 6;
  const int wm = wave >> 1;
  const int wn = wave & 1;
  const int row0 = blockIdx.x * 128 + wm * 64;
  const int col0 = blockIdx.y * 128 + wn * 64;
  const int lr = lane & 15;
  const int kg = (lane >> 4) * 8;

  f32x4 acc[4][4];
  const f32x4 vzero = {0.f, 0.f, 0.f, 0.f};
#pragma unroll
  for (int m = 0; m < 4; ++m)
#pragma unroll
    for (int n = 0; n < 4; ++n) acc[m][n] = vzero;

  size_t aoff[4], boff[4];
#pragma unroll
  for (int m = 0; m < 4; ++m) {
    int r = row0 + m * 16 + lr;
    if (r > M - 1) r = M - 1;  // clamp tail reads (writes guarded below)
    aoff[m] = (size_t)r * K + kg;
  }
#pragma unroll
  for (int n = 0; n < 4; ++n)
    boff[n] = (size_t)(col0 + n * 16 + lr) * K + kg;

#pragma unroll 1
  for (int k0 = 0; k0 < K; k0 += 32) {
    f16x8 ah[4], al[4], bh[4], bl[4];
#pragma unroll
    for (int m = 0; m < 4; ++m) {
      ah[m] = *(const f16x8*)(Ah + aoff[m] + k0);
      al[m] = *(const f16x8*)(Al + aoff[m] + k0);
    }
#pragma unroll
    for (int n = 0; n < 4; ++n) {
      bh[n] = *(const f16x8*)(Bth + boff[n] + k0);
      bl[n] = *(const f16x8*)(Btl + boff[n] + k0);
    }
#pragma unroll
    for (int m = 0; m < 4; ++m)
#pragma unroll
      for (int n = 0; n < 4; ++n) {
        acc[m][n] = __builtin_amdgcn_mfma_f32_16x16x32_f16(ah[m], bh[n], acc[m][n], 0, 0, 0);
        acc[m][n] = __builtin_amdgcn_mfma_f32_16x16x32_f16(ah[m], bl[n], acc[m][n], 0, 0, 0);
        acc[m][n] = __builtin_amdgcn_mfma_f32_16x16x32_f16(al[m], bh[n], acc[m][n], 0, 0, 0);
      }
  }

  const int rbase = (lane >> 4) * 4;
#pragma unroll
  for (int m = 0; m < 4; ++m) {
#pragma unroll
    for (int r = 0; r < 4; ++r) {
      int row = row0 + m * 16 + rbase + r;
      if (row < M) {
#pragma unroll
        for (int n = 0; n < 4; ++n) {
          int col = col0 + n * 16 + lr;
          float v = acc[m][n][r];
          if (bias) v += bias[col];
          f16 h = (f16)v;
          size_t o = (size_t)row * Nc + col;
          Ch[o] = h;
          Cl[o] = (f16)(v - (float)h);
        }
      }
    }
  }
}

// ---------------- degree accumulation ----------------
__global__ __launch_bounds__(256) void deg_accum(
    const int* __restrict__ dst, const float* __restrict__ ew,
    float* deg, int* cnt, int E) {
  int e = blockIdx.x * 256 + threadIdx.x;
  if (e < E) {
    int d = dst[e];
    atomicAdd(&deg[d], ew[e]);
    atomicAdd(&cnt[d], 1);
  }
}

// ---------------- hierarchical exclusive scan + dinv ----------------
__global__ __launch_bounds__(256) void scan_p1(const int* __restrict__ cnt,
                                               const float* __restrict__ deg,
                                               float* __restrict__ dinv,
                                               int* __restrict__ bsum, int n) {
  __shared__ int s[256];
  int i = blockIdx.x * 256 + threadIdx.x;
  s[threadIdx.x] = (i < n) ? cnt[i] : 0;
  if (i < n) dinv[i] = rsqrtf(deg[i] + 1.0f);
  __syncthreads();
  for (int off = 128; off > 0; off >>= 1) {
    if (threadIdx.x < off) s[threadIdx.x] += s[threadIdx.x + off];
    __syncthreads();
  }
  if (threadIdx.x == 0) bsum[blockIdx.x] = s[0];
}

__global__ __launch_bounds__(256) void scan_p2(int* __restrict__ bsum, int nb,
                                               int* __restrict__ total_out) {
  __shared__ int s[256];
  int t = threadIdx.x;
  int v = (t < nb) ? bsum[t] : 0;
  s[t] = v;
  __syncthreads();
  for (int off = 1; off < 256; off <<= 1) {
    int u = (t >= off) ? s[t - off] : 0;
    __syncthreads();
    s[t] += u;
    __syncthreads();
  }
  if (t < nb) bsum[t] = s[t] - v;
  if (t == 255) *total_out = s[255];
}

__global__ __launch_bounds__(256) void scan_p3(const int* __restrict__ cnt,
                                               const int* __restrict__ bsum,
                                               int* __restrict__ row_ptr, int n) {
  __shared__ int s[256];
  int i = blockIdx.x * 256 + threadIdx.x;
  int t = threadIdx.x;
  int v = (i < n) ? cnt[i] : 0;
  s[t] = v;
  __syncthreads();
  for (int off = 1; off < 256; off <<= 1) {
    int u = (t >= off) ? s[t - off] : 0;
    __syncthreads();
    s[t] += u;
    __syncthreads();
  }
  if (i < n) row_ptr[i] = bsum[blockIdx.x] + s[t] - v;
}

// ---------------- CSR fill ----------------
__global__ __launch_bounds__(256) void csr_fill(
    const int* __restrict__ src, const int* __restrict__ dst,
    const float* __restrict__ ew, const float* __restrict__ dinv,
    const int* __restrict__ row_ptr, int* cursor,
    int* __restrict__ csr_src, float* __restrict__ csr_coef, int E) {
  int e = blockIdx.x * 256 + threadIdx.x;
  if (e < E) {
    int s = src[e], d = dst[e];
    int pos = atomicAdd(&cursor[d], 1);
    int idx = row_ptr[d] + pos;
    csr_src[idx] = s;
    csr_coef[idx] = dinv[s] * ew[e] * dinv[d];
  }
}

// -- aggregation + bias + ELU on (hi,lo) planes: wave/node, pipelined entries --
__global__ __launch_bounds__(256) void gather_elu(
    const f16* __restrict__ Hh, const f16* __restrict__ Hl,
    const float* __restrict__ dinv, const int* __restrict__ row_ptr,
    const int* __restrict__ csr_src, const float* __restrict__ csr_coef,
    const float* __restrict__ bias,
    f16* __restrict__ Oh, f16* __restrict__ Ol) {
  const int wave = threadIdx.x >> 6;
  const int lane = threadIdx.x & 63;
  const int n = blockIdx.x * 4 + wave;
  if (n >= N_NODES) return;
  const f16x4* hh4 = (const f16x4*)Hh;  // 64 f16x4 per row
  const f16x4* hl4 = (const f16x4*)Hl;
  const int start = row_ptr[n], end = row_ptr[n + 1];
  const float di = dinv[n];
  const float cself = di * di;
  size_t self = (size_t)n * 64 + lane;
  f16x4 sh = hh4[self], sl = hl4[self];
  float a0 = cself * ((float)sh[0] + (float)sl[0]);
  float a1 = cself * ((float)sh[1] + (float)sl[1]);
  float a2 = cself * ((float)sh[2] + (float)sl[2]);
  float a3 = cself * ((float)sh[3] + (float)sl[3]);
  const int npairs = (end - start) >> 1;
  int e = start;
  if (npairs > 0) {
    int s0 = csr_src[e], s1 = csr_src[e + 1];
    float w0 = csr_coef[e], w1 = csr_coef[e + 1];
    for (int p = 1; p < npairs; ++p) {
      e += 2;
      size_t o0 = (size_t)s0 * 64 + lane, o1 = (size_t)s1 * 64 + lane;
      f16x4 h0 = hh4[o0], l0 = hl4[o0];
      f16x4 h1 = hh4[o1], l1 = hl4[o1];
      int t0 = csr_src[e], t1 = csr_src[e + 1];
      float u0 = csr_coef[e], u1 = csr_coef[e + 1];
      a0 += w0 * ((float)h0[0] + (float)l0[0]) + w1 * ((float)h1[0] + (float)l1[0]);
      a1 += w0 * ((float)h0[1] + (float)l0[1]) + w1 * ((float)h1[1] + (float)l1[1]);
      a2 += w0 * ((float)h0[2] + (float)l0[2]) + w1 * ((float)h1[2] + (float)l1[2]);
      a3 += w0 * ((float)h0[3] + (float)l0[3]) + w1 * ((float)h1[3] + (float)l1[3]);
      s0 = t0; s1 = t1; w0 = u0; w1 = u1;
    }
    size_t o0 = (size_t)s0 * 64 + lane, o1 = (size_t)s1 * 64 + lane;
    f16x4 h0 = hh4[o0], l0 = hl4[o0];
    f16x4 h1 = hh4[o1], l1 = hl4[o1];
    a0 += w0 * ((float)h0[0] + (float)l0[0]) + w1 * ((float)h1[0] + (float)l1[0]);
    a1 += w0 * ((float)h0[1] + (float)l0[1]) + w1 * ((float)h1[1] + (float)l1[1]);
    a2 += w0 * ((float)h0[2] + (float)l0[2]) + w1 * ((float)h1[2] + (float)l1[2]);
    a3 += w0 * ((float)h0[3] + (float)l0[3]) + w1 * ((float)h1[3] + (float)l1[3]);
    e += 2;
  }
  if (e < end) {
    int s0 = csr_src[e];
    float w0 = csr_coef[e];
    size_t o0 = (size_t)s0 * 64 + lane;
    f16x4 h0 = hh4[o0], l0 = hl4[o0];
    a0 += w0 * ((float)h0[0] + (float)l0[0]);
    a1 += w0 * ((float)h0[1] + (float)l0[1]);
    a2 += w0 * ((float)h0[2] + (float)l0[2]);
    a3 += w0 * ((float)h0[3] + (float)l0[3]);
  }
  float4 bb = ((const float4*)bias)[lane];
  a0 += bb.x; a1 += bb.y; a2 += bb.z; a3 += bb.w;
  a0 = (a0 > 0.f) ? a0 : expm1f(a0);
  a1 = (a1 > 0.f) ? a1 : expm1f(a1);
  a2 = (a2 > 0.f) ? a2 : expm1f(a2);
  a3 = (a3 > 0.f) ? a3 : expm1f(a3);
  f16x4 oh, ol;
  f16 q0 = (f16)a0; oh[0] = q0; ol[0] = (f16)(a0 - (float)q0);
  f16 q1 = (f16)a1; oh[1] = q1; ol[1] = (f16)(a1 - (float)q1);
  f16 q2 = (f16)a2; oh[2] = q2; ol[2] = (f16)(a2 - (float)q2);
  f16 q3 = (f16)a3; oh[3] = q3; ol[3] = (f16)(a3 - (float)q3);
  ((f16x4*)Oh)[self] = oh;
  ((f16x4*)Ol)[self] = ol;
}

// ---------------- pooling (sorted batch -> ranges) + final linear -------------
__global__ __launch_bounds__(256) void find_start(const int* __restrict__ batch,
                                                  int* __restrict__ gstart) {
  int g = blockIdx.x * 256 + threadIdx.x;
  if (g <= NUM_GRAPHS) {
    int lo = 0, hi = N_NODES;
    while (lo < hi) {
      int mid = (lo + hi) >> 1;
      if (batch[mid] < g) lo = mid + 1; else hi = mid;
    }
    gstart[g] = lo;
  }
}

__global__ __launch_bounds__(256) void pool_final(
    const f16* __restrict__ Hh, const f16* __restrict__ Hl,
    const int* __restrict__ gstart,
    const float* __restrict__ W, const float* __restrict__ b,
    float* __restrict__ out) {
  int g = blockIdx.x;
  __shared__ float part[NCLS * 256];
  int f = threadIdx.x;
  int s = gstart[g], e = gstart[g + 1];
  float sum = 0.f;
  for (int n = s; n < e; ++n) {
    size_t o = (size_t)n * HID + f;
    sum += (float)Hh[o] + (float)Hl[o];
  }
  float v = sum / fmaxf((float)(e - s), 1.0f);
#pragma unroll
  for (int c = 0; c < NCLS; ++c) part[c * 256 + f] = v * W[f * NCLS + c];
  __syncthreads();
  for (int off = 128; off > 0; off >>= 1) {
    if (f < off) {
#pragma unroll
      for (int c = 0; c < NCLS; ++c) part[c * 256 + f] += part[c * 256 + f + off];
    }
    __syncthreads();
  }
  if (f < NCLS) out[g * NCLS + f] = part[f * 256] + b[f];
}

extern "C" void kernel_launch(void* const* d_in, const int* in_sizes, int n_in,
                              void* d_out, int out_size, void* d_ws, size_t ws_size,
                              hipStream_t stream) {
  const float* x = (const float*)d_in[0];
  const int* ei = (const int*)d_in[1];
  const int* e_src = ei;
  const int* e_dst = ei + N_EDGES;
  const float* ea = (const float*)d_in[2];
  // d_in[3] = edge_type: unused (edge_dim=1 mixing carries no per-type params)
  const int* batch = (const int*)d_in[4];
  const float* enc1_w = (const float*)d_in[5];
  const float* enc1_b = (const float*)d_in[6];
  const float* enc2_w = (const float*)d_in[7];
  const float* enc2_b = (const float*)d_in[8];
  const float* conv_ws = (const float*)d_in[9];
  const float* conv_bs = (const float*)d_in[10];
  const float* lin1_w = (const float*)d_in[11];
  const float* lin1_b = (const float*)d_in[12];
  float* out = (float*)d_out;

  char* w = (char*)d_ws;
  size_t off = 0;
  auto alloc = [&](size_t bytes) {
    size_t o = off;
    off = (off + bytes + 255) & ~(size_t)255;
    return (void*)(w + o);
  };
  const size_t PLANE = (size_t)N_NODES * HID;  // 12.8M f16 elements
  f16* Ahp = (f16*)alloc(PLANE * 2);
  f16* Alp = (f16*)alloc(PLANE * 2);
  f16* Bhp = (f16*)alloc(PLANE * 2);
  f16* Blp = (f16*)alloc(PLANE * 2);
  // transposed-split weights: [enc1t 16384][enc2t 32768][convt 4*65536]
  const size_t WTOT = 16384 + 32768 + 4 * 65536;
  f16* wth = (f16*)alloc(WTOT * 2);
  f16* wtl = (f16*)alloc(WTOT * 2);
  float* deg = (float*)alloc((size_t)N_NODES * 4);
  float* dinv = (float*)alloc((size_t)N_NODES * 4);
  int* cnt = (int*)alloc((size_t)N_NODES * 4);
  int* row_ptr = (int*)alloc((size_t)(N_NODES + 1) * 4);
  int* cursor = (int*)alloc((size_t)N_NODES * 4);
  int* bsum = (int*)alloc((size_t)256 * 4);
  int* csr_src = (int*)alloc((size_t)N_EDGES * 4);
  float* csr_coef = (float*)alloc((size_t)N_EDGES * 4);
  int* gstart = (int*)alloc((size_t)(NUM_GRAPHS + 1) * 4);
  (void)ws_size; (void)in_sizes; (void)n_in; (void)out_size;

  hipMemsetAsync(deg, 0, (size_t)N_NODES * 4, stream);
  hipMemsetAsync(cnt, 0, (size_t)N_NODES * 4, stream);
  hipMemsetAsync(cursor, 0, (size_t)N_NODES * 4, stream);

  const int nb_nodes = (N_NODES + 255) / 256;
  const int nb_edges = (N_EDGES + 255) / 256;

  // graph normalization + CSR (feature-independent)
  deg_accum<<<nb_edges, 256, 0, stream>>>(e_dst, ea, deg, cnt, N_EDGES);
  scan_p1<<<nb_nodes, 256, 0, stream>>>(cnt, deg, dinv, bsum, N_NODES);
  scan_p2<<<1, 256, 0, stream>>>(bsum, nb_nodes, row_ptr + N_NODES);
  scan_p3<<<nb_nodes, 256, 0, stream>>>(cnt, bsum, row_ptr, N_NODES);
  csr_fill<<<nb_edges, 256, 0, stream>>>(e_src, e_dst, ea, dinv, row_ptr, cursor,
                                         csr_src, csr_coef, N_EDGES);
  find_start<<<(NUM_GRAPHS + 256) / 256, 256, 0, stream>>>(batch, gstart);

  // split x into f16 planes (aliased into B planes; dead after enc1)
  f16* xh = Bhp;
  f16* xl = Blp;
  {
    int n4 = N_NODES * F_IN / 4;
    split_f32<<<(n4 + 255) / 256, 256, 0, stream>>>(x, xh, xl, n4);
  }
  // weight transpose+split
  f16* e1h = wth;            f16* e1l = wtl;
  f16* e2h = wth + 16384;    f16* e2l = wtl + 16384;
  f16* cvh = wth + 49152;    f16* cvl = wtl + 49152;
  tsplit<<<(16384 + 255) / 256, 256, 0, stream>>>(enc1_w, e1h, e1l, F_IN, F_IN, 16384);
  tsplit<<<(32768 + 255) / 256, 256, 0, stream>>>(enc2_w, e2h, e2l, F_IN, HID, 32768);
  tsplit<<<(262144 + 255) / 256, 256, 0, stream>>>(conv_ws, cvh, cvl, HID, HID, 262144);

  const int gR = (N_NODES + 127) / 128;  // 391

  // enc1: (x)@W1+b1 -> h0 planes (A), [50000][128]
  {
    dim3 grid(gR, 1);
    gemm_mfma<<<grid, 256, 0, stream>>>(xh, xl, e1h, e1l, enc1_b,
                                        Ahp, Alp, N_NODES, F_IN, F_IN);
  }
  // enc2: h0@W2+b2 -> h planes (B), [50000][256]  (overwrites dead x planes)
  {
    dim3 grid(gR, 2);
    gemm_mfma<<<grid, 256, 0, stream>>>(Ahp, Alp, e2h, e2l, enc2_b,
                                        Bhp, Blp, N_NODES, F_IN, HID);
  }

  // 4 GCN layers: hW = h@W (B->A); aggregate+bias+ELU (A->B)
  for (int layer = 0; layer < 4; ++layer) {
    dim3 grid(gR, 2);
    gemm_mfma<<<grid, 256, 0, stream>>>(Bhp, Blp,
                                        cvh + (size_t)layer * 65536,
                                        cvl + (size_t)layer * 65536,
                                        nullptr, Ahp, Alp, N_NODES, HID, HID);
    gather_elu<<<(N_NODES + 3) / 4, 256, 0, stream>>>(
        Ahp, Alp, dinv, row_ptr, csr_src, csr_coef,
        conv_bs + (size_t)layer * HID, Bhp, Blp);
  }

  // deterministic mean-pool per graph + final linear (fused)
  pool_final<<<NUM_GRAPHS, 256, 0, stream>>>(Bhp, Blp, gstart, lin1_w, lin1_b, out);
}